// Round 7
// baseline (728.832 us; speedup 1.0000x reference)
//
#include <hip/hip_runtime.h>
#include <hip/hip_bf16.h>

// Problem constants (match reference)
#define G_GROUPS 8192
#define M_MEMB   32
#define D_DIM    128
#define H_ATT    16

typedef __attribute__((ext_vector_type(8))) short s16x8;   // 8 bf16 (4 VGPRs)
typedef __attribute__((ext_vector_type(4))) float f32x4;   // MFMA accumulator

__device__ __forceinline__ unsigned short f2bf_rne(float x) {
    union { __hip_bfloat16 b; unsigned short u; } c;
    c.b = __float2bfloat16(x);
    return c.u;
}

// ---------------------------------------------------------------------------
// Kernel 1: per-group member gather + AGREE attention + group embedding add.
// One block per group, 256 threads = 8 threads per member (32 members).
// ---------------------------------------------------------------------------
__global__ __launch_bounds__(256) void k_attn(
    const int* __restrict__ group_inputs, const int* __restrict__ members,
    const float* __restrict__ member_mask, const float* __restrict__ user_embedding,
    const float* __restrict__ user_table, const float* __restrict__ group_table,
    const float* __restrict__ aw1, const float* __restrict__ ab1,
    const float* __restrict__ aw2, const float* __restrict__ ab2,
    float* __restrict__ GE)
{
    __shared__ float sw1[H_ATT][132];   // aw1 transposed [h][d], padded pitch
    __shared__ float sw2[H_ATT];
    __shared__ float sb1[H_ATT];
    __shared__ float slog[M_MEMB];
    __shared__ float spart[4][D_DIM];   // per-wave partial weighted sums

    const int t = threadIdx.x;
    const int g = blockIdx.x;

    // Stage aw1 transposed: aw1 is [128][16] row-major; 2048 floats / 256 thr = 8.
    {
        int d  = t >> 1;
        int h0 = (t & 1) * 8;
        float4 v0 = *(const float4*)&aw1[d * 16 + h0];
        float4 v1 = *(const float4*)&aw1[d * 16 + h0 + 4];
        sw1[h0 + 0][d] = v0.x; sw1[h0 + 1][d] = v0.y;
        sw1[h0 + 2][d] = v0.z; sw1[h0 + 3][d] = v0.w;
        sw1[h0 + 4][d] = v1.x; sw1[h0 + 5][d] = v1.y;
        sw1[h0 + 6][d] = v1.z; sw1[h0 + 7][d] = v1.w;
    }
    if (t < H_ATT) { sw2[t] = aw2[t]; sb1[t] = ab1[t]; }
    __syncthreads();

    const int m   = t >> 3;   // member 0..31
    const int sub = t & 7;    // dim-chunk lane 0..7

    const int   u   = members[g * M_MEMB + m];
    const float msk = member_mask[g * M_MEMB + m];

    // Member embedding chunk: e = user_table[u] + user_embedding[u]
    float4 e[4];
#pragma unroll
    for (int ii = 0; ii < 4; ++ii) {
        int d = sub * 4 + 32 * ii;
        float4 a = *(const float4*)&user_table[(size_t)u * D_DIM + d];
        float4 b = *(const float4*)&user_embedding[(size_t)u * D_DIM + d];
        e[ii] = make_float4(a.x + b.x, a.y + b.y, a.z + b.z, a.w + b.w);
    }

    float ph[H_ATT];
#pragma unroll
    for (int h = 0; h < H_ATT; ++h) ph[h] = 0.f;
#pragma unroll
    for (int h = 0; h < H_ATT; ++h) {
#pragma unroll
        for (int ii = 0; ii < 4; ++ii) {
            int d = sub * 4 + 32 * ii;
            float4 w4 = *(const float4*)&sw1[h][d];
            ph[h] += e[ii].x * w4.x + e[ii].y * w4.y + e[ii].z * w4.z + e[ii].w * w4.w;
        }
    }
#pragma unroll
    for (int h = 0; h < H_ATT; ++h) {
        ph[h] += __shfl_xor(ph[h], 1, 64);
        ph[h] += __shfl_xor(ph[h], 2, 64);
        ph[h] += __shfl_xor(ph[h], 4, 64);
    }
    float logit = ab2[0];
#pragma unroll
    for (int h = 0; h < H_ATT; ++h) {
        float hv = fmaxf(ph[h] + sb1[h], 0.f);
        logit += hv * sw2[h];
    }
    if (!(msk > 0.f)) logit = -1e9f;
    if (sub == 0) slog[m] = logit;
    __syncthreads();

    float mx = -1e30f;
#pragma unroll
    for (int i = 0; i < M_MEMB; ++i) mx = fmaxf(mx, slog[i]);
    float se = 0.f;
#pragma unroll
    for (int i = 0; i < M_MEMB; ++i) se += expf(slog[i] - mx);
    const float w = expf(slog[m] - mx) / se;

    float4 we[4];
#pragma unroll
    for (int ii = 0; ii < 4; ++ii)
        we[ii] = make_float4(e[ii].x * w, e[ii].y * w, e[ii].z * w, e[ii].w * w);
#pragma unroll
    for (int ii = 0; ii < 4; ++ii) {
        float* c = (float*)&we[ii];
#pragma unroll
        for (int j = 0; j < 4; ++j) {
            c[j] += __shfl_xor(c[j], 8, 64);
            c[j] += __shfl_xor(c[j], 16, 64);
            c[j] += __shfl_xor(c[j], 32, 64);
        }
    }
    const int wv = t >> 6;
    if ((t & 63) < 8) {
#pragma unroll
        for (int ii = 0; ii < 4; ++ii)
            *(float4*)&spart[wv][sub * 4 + 32 * ii] = we[ii];
    }
    __syncthreads();

    if (t < D_DIM) {
        int d = t;
        float s = spart[0][d] + spart[1][d] + spart[2][d] + spart[3][d];
        int gi = group_inputs[g];
        GE[(size_t)g * D_DIM + d] = s + group_table[(size_t)gi * D_DIM + d];
    }
}

// ---------------------------------------------------------------------------
// Kernel 2: small GEMM  X[8192,128] = A[8192,128] @ W[128,128], emitted as
// split-bf16, transposed, 8-k-packed:  Xt8{h,l}[k/8][col][k%8]  (bf16)
// so the big GEMM's B-fragments are single contiguous 16B loads.
// 32 rows (k's) per block, 4x4 register tile per thread.
// ---------------------------------------------------------------------------
__global__ __launch_bounds__(256) void k_small_gemm_xt(
    const float* __restrict__ A, const float* __restrict__ W,
    unsigned short* __restrict__ Xth, unsigned short* __restrict__ Xtl)
{
    __shared__ float Ws[64][128];
    __shared__ float ATs[128][36];

    const int t = threadIdx.x;
    const int row0 = blockIdx.x * 32;
    const int tx = t & 31, ty = t >> 5;

#pragma unroll
    for (int i = 0; i < 4; ++i) {
        int f = t + 256 * i;
        int r = f >> 5, c4 = f & 31;
        float4 v = *(const float4*)&A[(size_t)(row0 + r) * 128 + c4 * 4];
        ATs[c4 * 4 + 0][r] = v.x; ATs[c4 * 4 + 1][r] = v.y;
        ATs[c4 * 4 + 2][r] = v.z; ATs[c4 * 4 + 3][r] = v.w;
    }

    float acc[4][4];
#pragma unroll
    for (int i = 0; i < 4; ++i)
#pragma unroll
        for (int j = 0; j < 4; ++j) acc[i][j] = 0.f;

    for (int kh = 0; kh < 2; ++kh) {
        __syncthreads();
#pragma unroll
        for (int i = 0; i < 8; ++i) {
            int f = t + 256 * i;
            int r = f >> 5, c4 = f & 31;
            *(float4*)&Ws[r][c4 * 4] = *(const float4*)&W[(size_t)(kh * 64 + r) * 128 + c4 * 4];
        }
        __syncthreads();
#pragma unroll 8
        for (int k = 0; k < 64; ++k) {
            float4 a4 = *(const float4*)&ATs[kh * 64 + k][ty * 4];
            float4 b4 = *(const float4*)&Ws[k][tx * 4];
            const float* av = (const float*)&a4;
            const float* bv = (const float*)&b4;
#pragma unroll
            for (int i = 0; i < 4; ++i)
#pragma unroll
                for (int j = 0; j < 4; ++j)
                    acc[i][j] += av[i] * bv[j];
        }
    }

    // Epilogue: split each value into hi (bf16 truncate) + lo (bf16 RNE of
    // remainder); write transposed, 8-k-packed. k = row index here.
    // NOTE: stores are two packed-uint writes, NOT ushort4 — off can be
    // 4 mod 8 (k&7==4), and an 8B-aligned ushort4 store there is UB.
    const int k = row0 + ty * 4;                   // 4 consecutive k's, k%4==0
    const size_t gbase = ((size_t)(k >> 3) * 128) * 8 + (k & 7);
#pragma unroll
    for (int j = 0; j < 4; ++j) {
        int col = tx * 4 + j;
        unsigned int hu[2] = {0, 0}, lu[2] = {0, 0};
#pragma unroll
        for (int i = 0; i < 4; ++i) {
            float v = acc[i][j];
            unsigned int b = __float_as_uint(v);
            unsigned int hbits = b >> 16;
            float hf = __uint_as_float(b & 0xFFFF0000u);
            unsigned int lbits = f2bf_rne(v - hf);
            hu[i >> 1] |= hbits << ((i & 1) * 16);
            lu[i >> 1] |= lbits << ((i & 1) * 16);
        }
        size_t off = gbase + (size_t)col * 8;      // off % 4 == 0 always
        *(unsigned int*)&Xth[off]     = hu[0];
        *(unsigned int*)&Xth[off + 2] = hu[1];
        *(unsigned int*)&Xtl[off]     = lu[0];
        *(unsigned int*)&Xtl[off + 2] = lu[1];
    }
}

// ---------------------------------------------------------------------------
// Kernel 3: big GEMM (or K-split partial) via split-bf16 MFMA:
//   Out[8192,128] (+)= H[rows, k-range] @ X[k-range, 128], optional relu.
// Block: 128 rows x 128 cols, 4 waves each owning a 64x64 wave-tile
// (4x4 fragments of v_mfma_f32_16x16x32_bf16). BK=64 (2 k-steps).
// A (H) is reg-staged fp32 -> split hi/lo bf16 -> XOR-swizzled LDS.
// B (Xt8) fragments load straight from global (L2-resident, 16B/lane).
// 3 MFMA terms: Ah*Bh + Ah*Bl + Al*Bh  (Al*Bl dropped, ~2^-15 rel).
// When S==1 this writes the final result (with relu) directly; when S>1
// each ks-slice writes a 4MB partial at Out + (ks<<20) and relu happens
// in k_reduce.
// ---------------------------------------------------------------------------
__global__ __launch_bounds__(256) void k_big_gemm_mfma(
    const float* __restrict__ H,
    const unsigned short* __restrict__ Xth, const unsigned short* __restrict__ Xtl,
    float* __restrict__ Out, int kper, int relu)
{
    __shared__ unsigned short Ah[128 * 64];   // 16 KB, byte-swizzled
    __shared__ unsigned short Al[128 * 64];   // 16 KB

    const int t    = threadIdx.x;
    const int row0 = blockIdx.x * 128;
    const int ks   = blockIdx.y;
    const int k0   = ks * kper;

    const int lane = t & 63;
    const int wid  = t >> 6;
    const int wr   = wid >> 1;       // wave row 0..1  (64 rows each)
    const int wc   = wid & 1;        // wave col 0..1  (64 cols each)
    const int lm   = lane & 15;      // fragment row/col within 16
    const int lk   = lane >> 4;      // k-group 0..3 (8 k's each)

    // staging mapping: thread t owns row r = t>>1, k-half (t&1)*32
    const int sr = t >> 1;
    const int sk = (t & 1) * 32;
    const float* hrow = H + (size_t)(row0 + sr) * G_GROUPS + k0 + sk;
    // swizzled LDS byte base for this thread's 4 16B write chunks
    const int swz_w = (sr & 7) << 4;
    const int wbase = sr * 128 + sk * 2;

    // A-fragment read offsets (swizzled) for mi=0..3, s=0..1
    int abyte[4][2];
#pragma unroll
    for (int mi = 0; mi < 4; ++mi) {
        int r = wr * 64 + mi * 16 + lm;
#pragma unroll
        for (int s = 0; s < 2; ++s)
            abyte[mi][s] = r * 128 + ((s * 64 + lk * 16) ^ ((r & 7) << 4));
    }
    // B per-lane column offsets (in ushort units) for nj=0..3
    int colb[4];
#pragma unroll
    for (int nj = 0; nj < 4; ++nj)
        colb[nj] = (wc * 64 + nj * 16 + lm) * 8;

    f32x4 acc[4][4];
#pragma unroll
    for (int mi = 0; mi < 4; ++mi)
#pragma unroll
        for (int nj = 0; nj < 4; ++nj)
            acc[mi][nj] = (f32x4)0.f;

    const int ktiles = kper / 64;

    // ---- prologue: stage tile 0 ----
    {
        float4 v[8];
#pragma unroll
        for (int w = 0; w < 8; ++w) v[w] = ((const float4*)hrow)[w];
#pragma unroll
        for (int w = 0; w < 4; ++w) {
            const float* p = (const float*)&v[2 * w];
            unsigned short h8[8], l8[8];
#pragma unroll
            for (int j = 0; j < 8; ++j) {
                unsigned int b = __float_as_uint(p[j]);
                h8[j] = (unsigned short)(b >> 16);
                float hf = __uint_as_float(b & 0xFFFF0000u);
                l8[j] = f2bf_rne(p[j] - hf);
            }
            int byte = (wbase + w * 16) ^ swz_w;
            *(s16x8*)((char*)Ah + byte) = *(const s16x8*)h8;
            *(s16x8*)((char*)Al + byte) = *(const s16x8*)l8;
        }
    }

    for (int kt = 0; kt < ktiles; ++kt) {
        __syncthreads();   // staged tile visible

        // T14: issue next tile's global loads before the MFMA work
        const bool has_next = (kt + 1) < ktiles;
        float4 v[8];
        if (has_next) {
            const float* nsrc = hrow + (size_t)(kt + 1) * 64;
#pragma unroll
            for (int w = 0; w < 8; ++w) v[w] = ((const float4*)nsrc)[w];
        }

#pragma unroll
        for (int s = 0; s < 2; ++s) {
            // B fragments: contiguous 16B global loads from packed Xt8
            const int kg = k0 + kt * 64 + s * 32;
            const size_t kterm = ((size_t)(kg >> 3) + lk) * 1024;
            s16x8 bh[4], bl[4];
#pragma unroll
            for (int nj = 0; nj < 4; ++nj) {
                bh[nj] = *(const s16x8*)&Xth[kterm + colb[nj]];
                bl[nj] = *(const s16x8*)&Xtl[kterm + colb[nj]];
            }
            // A fragments from swizzled LDS
            s16x8 ah[4], al[4];
#pragma unroll
            for (int mi = 0; mi < 4; ++mi) {
                ah[mi] = *(const s16x8*)((const char*)Ah + abyte[mi][s]);
                al[mi] = *(const s16x8*)((const char*)Al + abyte[mi][s]);
            }
#pragma unroll
            for (int mi = 0; mi < 4; ++mi)
#pragma unroll
                for (int nj = 0; nj < 4; ++nj) {
                    acc[mi][nj] = __builtin_amdgcn_mfma_f32_16x16x32_bf16(
                        ah[mi], bh[nj], acc[mi][nj], 0, 0, 0);
                    acc[mi][nj] = __builtin_amdgcn_mfma_f32_16x16x32_bf16(
                        ah[mi], bl[nj], acc[mi][nj], 0, 0, 0);
                    acc[mi][nj] = __builtin_amdgcn_mfma_f32_16x16x32_bf16(
                        al[mi], bh[nj], acc[mi][nj], 0, 0, 0);
                }
        }

        __syncthreads();   // all reads of this tile done

        if (has_next) {
#pragma unroll
            for (int w = 0; w < 4; ++w) {
                const float* p = (const float*)&v[2 * w];
                unsigned short h8[8], l8[8];
#pragma unroll
                for (int j = 0; j < 8; ++j) {
                    unsigned int b = __float_as_uint(p[j]);
                    h8[j] = (unsigned short)(b >> 16);
                    float hf = __uint_as_float(b & 0xFFFF0000u);
                    l8[j] = f2bf_rne(p[j] - hf);
                }
                int byte = (wbase + w * 16) ^ swz_w;
                *(s16x8*)((char*)Ah + byte) = *(const s16x8*)h8;
                *(s16x8*)((char*)Al + byte) = *(const s16x8*)l8;
            }
        }
    }

    // Epilogue: C/D layout col=lane&15, row=(lane>>4)*4+reg
    const size_t pbase = ((size_t)ks << 20);
#pragma unroll
    for (int mi = 0; mi < 4; ++mi) {
        int row = row0 + wr * 64 + mi * 16 + lk * 4;
#pragma unroll
        for (int nj = 0; nj < 4; ++nj) {
            int col = wc * 64 + nj * 16 + lm;
#pragma unroll
            for (int q = 0; q < 4; ++q) {
                float val = acc[mi][nj][q];
                if (relu) val = fmaxf(val, 0.f);
                Out[pbase + (size_t)(row + q) * 128 + col] = val;
            }
        }
    }
}

// ---------------------------------------------------------------------------
// Kernel 4: reduce K-split partials, optional relu.  (only used when S > 1)
// ---------------------------------------------------------------------------
__global__ __launch_bounds__(256) void k_reduce(
    const float* __restrict__ P, int S, float* __restrict__ out, int relu)
{
    int i = blockIdx.x * 256 + threadIdx.x;
    float4 s = make_float4(0.f, 0.f, 0.f, 0.f);
    for (int j = 0; j < S; ++j) {
        float4 v = *(const float4*)&P[((size_t)j << 20) + (size_t)i * 4];
        s.x += v.x; s.y += v.y; s.z += v.z; s.w += v.w;
    }
    if (relu) {
        s.x = fmaxf(s.x, 0.f); s.y = fmaxf(s.y, 0.f);
        s.z = fmaxf(s.z, 0.f); s.w = fmaxf(s.w, 0.f);
    }
    *(float4*)&out[(size_t)i * 4] = s;
}

// ---------------------------------------------------------------------------
extern "C" void kernel_launch(void* const* d_in, const int* in_sizes, int n_in,
                              void* d_out, int out_size, void* d_ws, size_t ws_size,
                              hipStream_t stream)
{
    (void)in_sizes; (void)n_in; (void)out_size;

    const int*   group_inputs   = (const int*)d_in[0];
    const int*   members        = (const int*)d_in[1];
    const float* member_mask    = (const float*)d_in[2];
    const float* user_embedding = (const float*)d_in[3];
    const float* Hm             = (const float*)d_in[4];
    const float* user_table     = (const float*)d_in[5];
    const float* group_table    = (const float*)d_in[6];
    const float* aw1            = (const float*)d_in[7];
    const float* ab1            = (const float*)d_in[8];
    const float* aw2            = (const float*)d_in[9];
    const float* ab2            = (const float*)d_in[10];
    const float* hw1            = (const float*)d_in[11];
    const float* hw2            = (const float*)d_in[12];

    char* wsb = (char*)d_ws;
    float*          A   = (float*)wsb;                               // 4 MB
    unsigned short* Xth = (unsigned short*)(wsb + ((size_t)4 << 20)); // 2 MB
    unsigned short* Xtl = (unsigned short*)(wsb + ((size_t)6 << 20)); // 2 MB
    float*          P   = (float*)(wsb + ((size_t)8 << 20));          // S*4 MB

    size_t pu = ws_size > ((size_t)8 << 20)
              ? (ws_size - ((size_t)8 << 20)) / ((size_t)4 << 20) : 0;
    int S = pu >= 8 ? 8 : (pu >= 4 ? 4 : (pu >= 2 ? 2 : 1));
    const int kper = G_GROUPS / S;
    const int NRED = (G_GROUPS * D_DIM / 4) / 256;

    // 1) gather + attention -> A = group_embeds
    k_attn<<<G_GROUPS, 256, 0, stream>>>(group_inputs, members, member_mask,
                                         user_embedding, user_table, group_table,
                                         aw1, ab1, aw2, ab2, A);
    // 2) Xt1 = split-bf16 transpose of (A @ hw1)
    k_small_gemm_xt<<<G_GROUPS / 32, 256, 0, stream>>>(A, hw1, Xth, Xtl);

    if (S == 1) {
        // Direct path: no partial buffer needed (min workspace = 8 MB).
        // 3) A = relu(H @ X1)
        k_big_gemm_mfma<<<dim3(G_GROUPS / 128, 1), 256, 0, stream>>>(
            Hm, Xth, Xtl, A, kper, 1);
        // 4) Xt2 = split-bf16 transpose of (A @ hw2)
        k_small_gemm_xt<<<G_GROUPS / 32, 256, 0, stream>>>(A, hw2, Xth, Xtl);
        // 5) out = H @ X2
        k_big_gemm_mfma<<<dim3(G_GROUPS / 128, 1), 256, 0, stream>>>(
            Hm, Xth, Xtl, (float*)d_out, kper, 0);
    } else {
        // 3) P = H @ X1 partials (MFMA, K-split)
        k_big_gemm_mfma<<<dim3(G_GROUPS / 128, S), 256, 0, stream>>>(
            Hm, Xth, Xtl, P, kper, 0);
        // 4) A = relu(sum P)
        k_reduce<<<NRED, 256, 0, stream>>>(P, S, A, 1);
        // 5) Xt2 = split-bf16 transpose of (A @ hw2)
        k_small_gemm_xt<<<G_GROUPS / 32, 256, 0, stream>>>(A, hw2, Xth, Xtl);
        // 6) P = H @ X2 partials
        k_big_gemm_mfma<<<dim3(G_GROUPS / 128, S), 256, 0, stream>>>(
            Hm, Xth, Xtl, P, kper, 0);
        // 7) out = sum P
        k_reduce<<<NRED, 256, 0, stream>>>(P, S, (float*)d_out, 0);
    }
}